// Round 2
// baseline (149.945 us; speedup 1.0000x reference)
//
#include <hip/hip_runtime.h>
#include <math.h>

#define T_LEN 4000
#define LPL   64          // elements per lane (64 lanes * 64 = 4096 >= 4000)
#define NQ    16          // float4 quads per lane

__device__ __forceinline__ float pcen_elem(float xv, float s) {
    const float ALPHA = 0.98f;
    const float DELTA = 2.0f;
    const float SQRT_DELTA = 1.4142135623730951f;
    const float EPS = 1e-6f;
    // (s+eps)^(-alpha) = exp2(-alpha * log2(s+eps)); s >= 0 so s+eps > 0
    float p = exp2f(-ALPHA * log2f(s + EPS));
    return sqrtf(fmaf(xv, p, DELTA)) - SQRT_DELTA;
}

__global__ __launch_bounds__(256, 4) void pcen_kernel(const float* __restrict__ x,
                                                      float* __restrict__ out,
                                                      int nrows) {
    const float ALPHA = 0.98f;
    const float OMA   = 0.02f;   // 1 - alpha

    const int lane = threadIdx.x & 63;
    const int wave = threadIdx.x >> 6;
    const int row  = blockIdx.x * 4 + wave;
    if (row >= nrows) return;

    const float* __restrict__ xr  = x   + (size_t)row * T_LEN;
    float* __restrict__       orow = out + (size_t)row * T_LEN;
    const int p = lane * LPL;    // this lane's segment start (256B-aligned)

    // ---- load segment into registers (aligned float4; tail quads zeroed) ----
    float xs[LPL];
#pragma unroll
    for (int q = 0; q < NQ; ++q) {
        const int t0 = p + 4 * q;
        float4 v;
        if (t0 < T_LEN) {
            v = *reinterpret_cast<const float4*>(xr + t0);
        } else {
            v = make_float4(0.f, 0.f, 0.f, 0.f);
        }
        xs[4 * q + 0] = v.x;
        xs[4 * q + 1] = v.y;
        xs[4 * q + 2] = v.z;
        xs[4 * q + 3] = v.w;
    }

    // ---- pass 1: local affine composition (a_loc, b_loc) over the segment ----
    // element t: A = (t==0 ? 0 : alpha), B = (t==0 ? x : (1-alpha)*x)
    // invalid tail elements (t >= T_LEN) contribute identity (1,0): skipped.
    float a_loc = 1.0f, b_loc = 0.0f;
#pragma unroll
    for (int q = 0; q < NQ; ++q) {
        const int t0 = p + 4 * q;
        if (t0 < T_LEN) {
#pragma unroll
            for (int j = 0; j < 4; ++j) {
                const int t = t0 + j;
                const float A = (t == 0) ? 0.0f : ALPHA;
                const float B = (t == 0) ? xs[4 * q + j] : OMA * xs[4 * q + j];
                b_loc = fmaf(A, b_loc, B);
                a_loc = A * a_loc;
            }
        }
    }

    // ---- Kogge-Stone inclusive scan of (a,b) pairs across 64 lanes ----
    // combine(earlier=(a1,b1), self=(a2,b2)) = (a2*a1, a2*b1 + b2)
#pragma unroll
    for (int d = 1; d < 64; d <<= 1) {
        const float au = __shfl_up(a_loc, d);
        const float bu = __shfl_up(b_loc, d);
        if (lane >= d) {
            b_loc = fmaf(a_loc, bu, b_loc);   // use pre-update a_loc
            a_loc = a_loc * au;
        }
    }
    // exclusive carry: state entering this lane's segment.
    // lane 0's pair has a=0 (A[0]=0), so every carry's multiplier is 0 ->
    // carry reduces to the b component alone.
    float s = __shfl_up(b_loc, 1);
    if (lane == 0) s = 0.0f;

    // ---- pass 2: replay recurrence with carry, epilogue, vector store ----
#pragma unroll
    for (int q = 0; q < NQ; ++q) {
        const int t0 = p + 4 * q;
        if (t0 < T_LEN) {
            float4 o;
            {
                const int t = t0 + 0;
                const float A = (t == 0) ? 0.0f : ALPHA;
                const float B = (t == 0) ? xs[4 * q + 0] : OMA * xs[4 * q + 0];
                s = fmaf(A, s, B);
                o.x = pcen_elem(xs[4 * q + 0], s);
            }
            s = fmaf(ALPHA, s, OMA * xs[4 * q + 1]);
            o.y = pcen_elem(xs[4 * q + 1], s);
            s = fmaf(ALPHA, s, OMA * xs[4 * q + 2]);
            o.z = pcen_elem(xs[4 * q + 2], s);
            s = fmaf(ALPHA, s, OMA * xs[4 * q + 3]);
            o.w = pcen_elem(xs[4 * q + 3], s);
            *reinterpret_cast<float4*>(orow + t0) = o;
        }
    }
}

extern "C" void kernel_launch(void* const* d_in, const int* in_sizes, int n_in,
                              void* d_out, int out_size, void* d_ws, size_t ws_size,
                              hipStream_t stream) {
    const float* x = (const float*)d_in[0];
    float* out = (float*)d_out;
    const int nrows = in_sizes[0] / T_LEN;   // 32*128 = 4096
    const int rows_per_block = 4;            // 256 threads = 4 waves = 4 rows
    const int grid = (nrows + rows_per_block - 1) / rows_per_block;
    pcen_kernel<<<grid, 256, 0, stream>>>(x, out, nrows);
}

// Round 3
// 112.867 us; speedup vs baseline: 1.3285x; 1.3285x over previous
//
#include <hip/hip_runtime.h>
#include <math.h>

#define T_LEN   4000
#define CHUNK   256            // 64 lanes * 4 elements
#define NCHUNK  16             // ceil(4000/256); last chunk has 160 valid elems

__device__ __forceinline__ float pcen_elem(float xv, float s) {
    const float ALPHA = 0.98f;
    const float DELTA = 2.0f;
    const float SQRT_DELTA = 1.4142135623730951f;
    const float EPS = 1e-6f;
    // (s+eps)^(-alpha) = exp2(-alpha * log2(s+eps)); s >= 0 so s+eps > 0
    float p = exp2f(-ALPHA * log2f(s + EPS));
    return sqrtf(fmaf(xv, p, DELTA)) - SQRT_DELTA;
}

__global__ __launch_bounds__(256, 4) void pcen_kernel(const float* __restrict__ x,
                                                      float* __restrict__ out,
                                                      int nrows) {
    const float ALPHA = 0.98f;
    const float OMA   = 0.02f;            // 1 - alpha
    const float A4    = 0.92236816f;      // alpha^4

    const int lane = threadIdx.x & 63;
    const int wave = threadIdx.x >> 6;
    const int row  = blockIdx.x * 4 + wave;
    if (row >= nrows) return;

    const float* __restrict__ xr   = x   + (size_t)row * T_LEN;
    float* __restrict__       orow = out + (size_t)row * T_LEN;

    float s_prev = 0.0f;   // smooth state entering the current chunk

#pragma unroll
    for (int c = 0; c < NCHUNK; ++c) {
        const int t0 = c * CHUNK + lane * 4;     // this lane's 4 consecutive t
        const bool valid = (t0 < T_LEN);          // T_LEN % 4 == 0: all-or-none

        // ---- coalesced load: wave covers 1KB of consecutive addresses ----
        float4 v = make_float4(0.f, 0.f, 0.f, 0.f);
        if (valid) v = *reinterpret_cast<const float4*>(xr + t0);

        // ---- local affine compose over the lane's 4 elements ----
        // element t: A=(t==0?0:alpha), B=(t==0? x : (1-alpha)*x)
        // invalid lanes contribute identity (1,0)
        float a, b;
        if (!valid) {
            a = 1.0f; b = 0.0f;
        } else if (t0 == 0) {                     // chunk 0, lane 0 holds t=0
            a = 0.0f;
            b = v.x;                              // s after t=0 is x[0]
            b = fmaf(ALPHA, b, OMA * v.y);
            b = fmaf(ALPHA, b, OMA * v.z);
            b = fmaf(ALPHA, b, OMA * v.w);
        } else {
            a = A4;
            b = OMA * v.x;
            b = fmaf(ALPHA, b, OMA * v.y);
            b = fmaf(ALPHA, b, OMA * v.z);
            b = fmaf(ALPHA, b, OMA * v.w);
        }

        // ---- Kogge-Stone inclusive scan of (a,b) across 64 lanes ----
        float ai = a, bi = b;
#pragma unroll
        for (int d = 1; d < 64; d <<= 1) {
            const float au = __shfl_up(ai, d);
            const float bu = __shfl_up(bi, d);
            if (lane >= d) {
                bi = fmaf(ai, bu, bi);            // pre-update ai
                ai = ai * au;
            }
        }

        // exclusive prefix for this lane (state entering its 4-segment)
        float ae = __shfl_up(ai, 1);
        float be = __shfl_up(bi, 1);
        if (lane == 0) { ae = 1.0f; be = 0.0f; }
        float s = fmaf(ae, s_prev, be);

        // carry for the next chunk: lane 63's inclusive result applied to s_prev
        const float a63 = __shfl(ai, 63);
        const float b63 = __shfl(bi, 63);
        const float s_next = fmaf(a63, s_prev, b63);

        // ---- replay the 4 elements, epilogue, coalesced store ----
        if (valid) {
            float4 o;
            if (t0 == 0) {
                s = v.x;                          // A=0, B=x0
            } else {
                s = fmaf(ALPHA, s, OMA * v.x);
            }
            o.x = pcen_elem(v.x, s);
            s = fmaf(ALPHA, s, OMA * v.y);
            o.y = pcen_elem(v.y, s);
            s = fmaf(ALPHA, s, OMA * v.z);
            o.z = pcen_elem(v.z, s);
            s = fmaf(ALPHA, s, OMA * v.w);
            o.w = pcen_elem(v.w, s);
            *reinterpret_cast<float4*>(orow + t0) = o;
        }

        s_prev = s_next;
    }
}

extern "C" void kernel_launch(void* const* d_in, const int* in_sizes, int n_in,
                              void* d_out, int out_size, void* d_ws, size_t ws_size,
                              hipStream_t stream) {
    const float* x = (const float*)d_in[0];
    float* out = (float*)d_out;
    const int nrows = in_sizes[0] / T_LEN;   // 32*128 = 4096
    const int rows_per_block = 4;            // 256 threads = 4 waves = 4 rows
    const int grid = (nrows + rows_per_block - 1) / rows_per_block;
    pcen_kernel<<<grid, 256, 0, stream>>>(x, out, nrows);
}